// Round 15
// baseline (297.646 us; speedup 1.0000x reference)
//
#include <hip/hip_runtime.h>

typedef __attribute__((ext_vector_type(8))) short short8v;
typedef __attribute__((ext_vector_type(4))) float f32x4;

typedef const __attribute__((address_space(1))) void gvoid_t;
typedef __attribute__((address_space(3))) void svoid_t;

__device__ __forceinline__ unsigned short f2b(float f) {
    unsigned u = __float_as_uint(f);
    unsigned r = (u + 0x7fffu + ((u >> 16) & 1u)) >> 16;
    return (unsigned short)r;
}
__device__ __forceinline__ float b2f(unsigned short h) {
    return __uint_as_float((unsigned)h << 16);
}

// ---------------- elementwise / setup kernels ----------------

// Fused: X = dt*A = scale*sigmoid(alpha_i)*(adj - I) -> XAb (bf16) + XATb (bf16 T)
__global__ void k_build_AT(const float* __restrict__ adj,
                           const float* __restrict__ alpha,
                           unsigned short* __restrict__ XAb,
                           unsigned short* __restrict__ XATb,
                           int n, float scale)
{
    __shared__ float tile[32][33];
    int bx = blockIdx.x * 32, by = blockIdx.y * 32;
    int tx = threadIdx.x, ty = threadIdx.y;
    #pragma unroll
    for (int r = 0; r < 32; r += 8) {
        int i = by + ty + r, j = bx + tx;
        float s = 1.f / (1.f + expf(-alpha[i]));
        float v = scale * s * (adj[(size_t)i * n + j] - (i == j ? 1.f : 0.f));
        XAb[(size_t)i * n + j] = f2b(v);
        tile[ty + r][tx] = v;
    }
    __syncthreads();
    #pragma unroll
    for (int r = 0; r < 32; r += 8)
        XATb[(size_t)(bx + ty + r) * n + by + tx] = f2b(tile[tx][ty + r]);
}

__global__ void k_build_EW(const float* __restrict__ w,
                           const float* __restrict__ d,
                           unsigned short* __restrict__ Eb,
                           unsigned short* __restrict__ Edb,
                           float* __restrict__ Edf, int h)
{
    int j = blockIdx.x * 256 + threadIdx.x;
    int i = blockIdx.y;
    if (j >= h) return;
    size_t idx = (size_t)i * h + j;
    float e = w[idx] - (i == j ? 1.f : 0.f);
    float dc = fminf(fmaxf(d[j], 0.f), 1.f);
    Eb[idx] = f2b(e);
    float ed = e * dc;
    Edb[idx] = f2b(ed);
    Edf[idx] = ed;
}

__global__ void k_build_R(const float* __restrict__ Ed,
                          const float* __restrict__ d,
                          float* __restrict__ R, int h, float dt)
{
    __shared__ float tile[32][33];
    int bx = blockIdx.x * 32, by = blockIdx.y * 32;
    int tx = threadIdx.x, ty = threadIdx.y;
    #pragma unroll
    for (int r = 0; r < 32; r += 8)
        tile[ty + r][tx] = Ed[(size_t)(bx + ty + r) * h + by + tx];
    __syncthreads();
    #pragma unroll
    for (int r = 0; r < 32; r += 8) {
        int i = by + ty + r, j = bx + tx;
        float v = Ed[(size_t)i * h + j] + tile[tx][ty + r];
        if (i == j) v += fminf(fmaxf(d[i], 0.f), 1.f) - 1.f;
        R[(size_t)i * h + j] = dt * v;
    }
}

// two transposes in one dispatch
__global__ void k_tsplit2(const float* __restrict__ in0,
                          const float* __restrict__ in1,
                          unsigned short* __restrict__ out0,
                          unsigned short* __restrict__ out1, int R, int C)
{
    __shared__ float tile[32][33];
    int bx = blockIdx.x * 32, by = blockIdx.y * 32;
    int tx = threadIdx.x, ty = threadIdx.y;
    #pragma unroll
    for (int r = 0; r < 32; r += 8)
        tile[ty + r][tx] = in0[(size_t)(by + ty + r) * C + bx + tx];
    __syncthreads();
    #pragma unroll
    for (int r = 0; r < 32; r += 8)
        out0[(size_t)(bx + ty + r) * R + by + tx] = f2b(tile[tx][ty + r]);
    __syncthreads();
    #pragma unroll
    for (int r = 0; r < 32; r += 8)
        tile[ty + r][tx] = in1[(size_t)(by + ty + r) * C + bx + tx];
    __syncthreads();
    #pragma unroll
    for (int r = 0; r < 32; r += 8)
        out1[(size_t)(bx + ty + r) * R + by + tx] = f2b(tile[tx][ty + r]);
}

// ---------------- dual bf16 MFMA GEMM ----------------
// Two independent GEMMs in ONE launch (blocks [0,nb0) -> a0, rest -> a1).
// R15: MW raised to the LDS limit (64x64 -> 5/CU, 64x32 -> 6/CU) so merged
// 1280-2048-block launches get real extra TLP (R8/R9: throughput ~ blocks/CU);
// short-GEMM blocks ordered FIRST so they ride the big GEMM's ramp, not tail.
// Per-GEMM structure identical to R13/R14: BK=64, 2-buffer counted-vmcnt
// pipeline, XOR-swizzled staging+reads (0 bank conflicts, R5-R14), XCD
// row-stripe swizzle on the logical grid.
// v  = alpha*acc + beta*D + g2*D2 + g3*b2f(Db) -> C, Cb, CbT
// v2 = pa*acc + pb*D + pc*b2f(Db)              -> C2, Cb2
// v3 = qa*acc + qb*D + qc*b2f(Db)              -> Cb3

struct GArgs {
    const unsigned short *A, *BT;
    float *C, *C2;
    unsigned short *Cb, *Cb2, *Cb3, *CbT;
    const float *D, *D2;
    const unsigned short *Db;
    int M, N, K, ngx, ngy;
    float alpha, beta, g2, g3, pa, pb, pc, qa, qb, qc;
};

template<int FM, int FN, int MW>
__global__ __launch_bounds__(256, MW)
void gemm2(GArgs a0, GArgs a1, int nb0)
{
    constexpr int BM = FM * 32, BN = FN * 32, BK = 64;
    constexpr int AIT = BM * BK / (8 * 256);
    constexpr int BIT = BN * BK / (8 * 256);
    constexpr int LPT = AIT + BIT;
    __shared__ unsigned short As[2][BM * BK];
    __shared__ unsigned short Bs[2][BN * BK];

    const bool second = ((int)blockIdx.x >= nb0);
    const GArgs& a = second ? a1 : a0;
    int bid = (int)blockIdx.x - (second ? nb0 : 0);

    // XCD row-stripe swizzle on the logical (ngy x ngx) grid (ngy % 8 == 0)
    int rpx = a.ngy >> 3;
    int q = bid & 7, c = bid >> 3;
    int by = q * rpx + (c % rpx);
    int bx = c / rpx;

    const int tid  = threadIdx.x;
    const int lane = tid & 63;
    const int wave = tid >> 6;
    const int wr = wave >> 1, wc = wave & 1;
    const int l16 = lane & 15, l4 = lane >> 4;
    const int brow = by * BM, bcol = bx * BN;
    const int K = a.K, N = a.N, M = a.M;

    f32x4 acc[FM][FN];
    #pragma unroll
    for (int m = 0; m < FM; ++m)
        #pragma unroll
        for (int j = 0; j < FN; ++j)
            acc[m][j] = (f32x4){0.f, 0.f, 0.f, 0.f};

    const unsigned short* Ab = a.A + (size_t)brow * K;
    const unsigned short* Bb = a.BT + (size_t)bcol * K;
    const int nt = K / BK;

    auto stage = [&](int b, int k0) {
        #pragma unroll
        for (int it = 0; it < AIT; ++it) {
            int cb = it * 256 + wave * 64;
            int ch = cb + lane;
            int r = ch >> 3, cc = ch & 7;
            int cs = cc ^ (r & 7);
            __builtin_amdgcn_global_load_lds(
                (gvoid_t*)(Ab + (size_t)r * K + k0 + cs * 8),
                (svoid_t*)(&As[b][cb * 8]), 16, 0, 0);
        }
        #pragma unroll
        for (int it = 0; it < BIT; ++it) {
            int cb = it * 256 + wave * 64;
            int ch = cb + lane;
            int r = ch >> 3, cc = ch & 7;
            int cs = cc ^ (r & 7);
            __builtin_amdgcn_global_load_lds(
                (gvoid_t*)(Bb + (size_t)r * K + k0 + cs * 8),
                (svoid_t*)(&Bs[b][cb * 8]), 16, 0, 0);
        }
    };

    stage(0, 0);
    stage(1, BK);

    for (int t = 0; t < nt; ++t) {
        const int cur = t & 1;
        if (t + 1 < nt) {
            asm volatile("s_waitcnt vmcnt(%0)" :: "i"(LPT) : "memory");
        } else {
            asm volatile("s_waitcnt vmcnt(0)" ::: "memory");
        }
        __builtin_amdgcn_s_barrier();
        asm volatile("" ::: "memory");
        __builtin_amdgcn_sched_barrier(0);

        short8v af[FM][2], bf[FN][2];
        #pragma unroll
        for (int m = 0; m < FM; ++m) {
            int r = wr * FM * 16 + m * 16 + l16;
            #pragma unroll
            for (int hf = 0; hf < 2; ++hf) {
                int cs = (hf * 4 + l4) ^ (r & 7);
                af[m][hf] = *(const short8v*)&As[cur][r * BK + cs * 8];
            }
        }
        #pragma unroll
        for (int j = 0; j < FN; ++j) {
            int r = wc * FN * 16 + j * 16 + l16;
            #pragma unroll
            for (int hf = 0; hf < 2; ++hf) {
                int cs = (hf * 4 + l4) ^ (r & 7);
                bf[j][hf] = *(const short8v*)&Bs[cur][r * BK + cs * 8];
            }
        }
        __builtin_amdgcn_s_setprio(1);
        #pragma unroll
        for (int hf = 0; hf < 2; ++hf)
            #pragma unroll
            for (int m = 0; m < FM; ++m)
                #pragma unroll
                for (int j = 0; j < FN; ++j)
                    acc[m][j] = __builtin_amdgcn_mfma_f32_16x16x32_bf16(
                        af[m][hf], bf[j][hf], acc[m][j], 0, 0, 0);
        __builtin_amdgcn_s_setprio(0);
        __builtin_amdgcn_sched_barrier(0);
        __builtin_amdgcn_s_barrier();
        asm volatile("" ::: "memory");
        if (t + 2 < nt) stage(cur, (t + 2) * BK);
    }

    #pragma unroll
    for (int m = 0; m < FM; ++m) {
        #pragma unroll
        for (int j = 0; j < FN; ++j) {
            const int row0 = brow + wr * FM * 16 + m * 16 + l4 * 4;
            const int col  = bcol + wc * FN * 16 + j * 16 + l16;
            float vv[4];
            #pragma unroll
            for (int q2 = 0; q2 < 4; ++q2) {
                size_t idx = (size_t)(row0 + q2) * N + col;
                float a0v = acc[m][j][q2];
                float v = a.alpha * a0v;
                float dv = 0.f, dbv = 0.f;
                if (a.D)  { dv = a.D[idx]; v = fmaf(a.beta, dv, v); }
                if (a.D2) v = fmaf(a.g2, a.D2[idx], v);
                if (a.Db) { dbv = b2f(a.Db[idx]); v = fmaf(a.g3, dbv, v); }
                vv[q2] = v;
                if (a.C)  a.C[idx] = v;
                if (a.Cb) a.Cb[idx] = f2b(v);
                if (a.C2 || a.Cb2) {
                    float v2 = a.pa * a0v;
                    if (a.D)  v2 = fmaf(a.pb, dv, v2);
                    if (a.Db) v2 = fmaf(a.pc, dbv, v2);
                    if (a.C2)  a.C2[idx] = v2;
                    if (a.Cb2) a.Cb2[idx] = f2b(v2);
                }
                if (a.Cb3) {
                    float v3 = a.qa * a0v;
                    if (a.D)  v3 = fmaf(a.qb, dv, v3);
                    if (a.Db) v3 = fmaf(a.qc, dbv, v3);
                    a.Cb3[idx] = f2b(v3);
                }
            }
            if (a.CbT) {
                ushort4 t4;
                t4.x = f2b(vv[0]); t4.y = f2b(vv[1]);
                t4.z = f2b(vv[2]); t4.w = f2b(vv[3]);
                *reinterpret_cast<ushort4*>(&a.CbT[(size_t)col * M + row0]) = t4;
            }
        }
    }
}

// ---------------- host orchestration ----------------

typedef unsigned short u16;

static GArgs mk(const u16* A, const u16* BT, float* C, float* C2,
                u16* Cb, u16* Cb2, u16* Cb3, u16* CbT,
                const float* D, const float* D2, const u16* Db,
                int M, int N, int K, int ngx, int ngy,
                float alpha, float beta, float g2, float g3,
                float pa, float pb, float pc,
                float qa, float qb, float qc)
{
    GArgs a;
    a.A = A; a.BT = BT; a.C = C; a.C2 = C2;
    a.Cb = Cb; a.Cb2 = Cb2; a.Cb3 = Cb3; a.CbT = CbT;
    a.D = D; a.D2 = D2; a.Db = Db;
    a.M = M; a.N = N; a.K = K; a.ngx = ngx; a.ngy = ngy;
    a.alpha = alpha; a.beta = beta; a.g2 = g2; a.g3 = g3;
    a.pa = pa; a.pb = pb; a.pc = pc; a.qa = qa; a.qb = qb; a.qc = qc;
    return a;
}

extern "C" void kernel_launch(void* const* d_in, const int* in_sizes, int n_in,
                              void* d_out, int out_size, void* d_ws, size_t ws_size,
                              hipStream_t stream)
{
    const float* x     = (const float*)d_in[0];   // [n, h]
    const float* x0    = (const float*)d_in[1];   // [n, h]
    const float* adj   = (const float*)d_in[2];   // [n, n]
    const float* alpha = (const float*)d_in[3];   // [n]
    const float* w     = (const float*)d_in[4];   // [h, h]
    const float* dvec  = (const float*)d_in[5];   // [h]

    const int n = in_sizes[3];      // 2048
    const int h = in_sizes[5];      // 1024
    const size_t MB = 1u << 20;
    char* ws = (char*)d_ws;

    // ---- workspace: non-overlapping regions (MiB offsets; peak 136 MiB) ----
    u16*   XAb   = (u16*)(ws + 0 * MB);      // 8
    u16*   XATb  = (u16*)(ws + 8 * MB);      // 8
    u16*   Mah   = (u16*)(ws + 16 * MB);     // 8
    u16*   Pmb   = (u16*)(ws + 24 * MB);     // 8
    u16*   M3ah  = (u16*)(ws + 32 * MB);     // 8
    u16*   MbT   = (u16*)(ws + 40 * MB);     // 2
    u16*   M3bTb = (u16*)(ws + 42 * MB);     // 2
    u16*   Eb_   = (u16*)(ws + 44 * MB);     // 2
    u16*   Edb   = (u16*)(ws + 46 * MB);     // 2
    float* Edf   = (float*)(ws + 48 * MB);   // 4
    float* R     = (float*)(ws + 52 * MB);   // 4
    float* XBf   = (float*)(ws + 56 * MB);   // 4
    u16*   XBb   = (u16*)(ws + 60 * MB);     // 2
    u16*   XBT   = (u16*)(ws + 62 * MB);     // 2
    float* P2f   = (float*)(ws + 64 * MB);   // 4
    u16*   P2b   = (u16*)(ws + 68 * MB);     // 2
    float* P3f   = (float*)(ws + 70 * MB);   // 4
    u16*   P3b   = (u16*)(ws + 74 * MB);     // 2
    u16*   x0T   = (u16*)(ws + 76 * MB);     // 4
    float* Ff    = (float*)(ws + 80 * MB);   // 8
    u16*   Fb    = (u16*)(ws + 88 * MB);     // 4
    u16*   FTb   = (u16*)(ws + 92 * MB);     // 4
    u16*   ub    = (u16*)(ws + 96 * MB);     // 4
    u16*   F2b   = (u16*)(ws + 100 * MB);    // 4
    u16*   F2Tb  = (u16*)(ws + 104 * MB);    // 4
    u16*   vb    = (u16*)(ws + 108 * MB);    // 4
    float* F3f   = (float*)(ws + 112 * MB);  // 8
    u16*   zt    = (u16*)(ws + 120 * MB);    // 4
    u16*   tb16  = (u16*)(ws + 124 * MB);    // 4
    float* za    = (float*)(ws + 128 * MB);  // 8

    const dim3 blk(256);
    const float dt = 0.1f;
    const u16* nu = nullptr;
    const float* nf = nullptr;

    // ===== setup =====
    k_build_AT<<<dim3(n / 32, n / 32), dim3(32, 8), 0, stream>>>(
        adj, alpha, XAb, XATb, n, 0.5f * dt);
    k_build_EW<<<dim3(h / 256, h), blk, 0, stream>>>(w, dvec, Eb_, Edb, Edf, h);
    k_build_R<<<dim3(h / 32, h / 32), dim3(32, 8), 0, stream>>>(Edf, dvec, R, h, dt);
    k_tsplit2<<<dim3(h / 32, n / 32), dim3(32, 8), 0, stream>>>(
        x0, x, x0T, zt, n, h);

    // ===== P1: B1 (h^3, 64x64, FIRST) || A1 (n^3, 64x64) =====
    // B1: XB = dt*(Ed @ E^T) + R -> XBf + XBb + XBT
    // A1: acc = X^2; Ma = X + X^2/2 -> Mah; Pm = X/2 + X^2/6 -> Pmb;
    //     M3a = 3X + 4.5X^2 -> M3ah
    {
        GArgs gB1 = mk(Edb, Eb_, XBf, nullptr, XBb, nullptr, nullptr, XBT,
                       R, nf, nu, h, h, h, h / 64, h / 64,
                       dt, 1.f, 0.f, 0.f, 0.f, 0.f, 0.f, 0.f, 0.f, 0.f);
        GArgs gA1 = mk(XAb, XATb, nullptr, nullptr, Mah, Pmb, M3ah, nullptr,
                       nf, nf, XAb, n, n, n, n / 64, n / 64,
                       0.5f, 0.f, 0.f, 1.f, 1.f / 6.f, 0.f, 0.5f, 4.5f, 0.f, 3.f);
        gemm2<2, 2, 5><<<dim3(256 + 1024), blk, 0, stream>>>(gB1, gA1, 256);
    }

    // ===== P2: B2 (h^3, FIRST) || F (K=2048) =====
    // B2: P2 = XB^2 -> P2f + P2b ; F = dt*(Pm@x0) + dt*x0 -> Ff + Fb + FTb
    {
        GArgs gB2 = mk(XBb, XBT, P2f, nullptr, P2b, nullptr, nullptr, nullptr,
                       nf, nf, nu, h, h, h, h / 32, h / 64,
                       1.f, 0.f, 0.f, 0.f, 0.f, 0.f, 0.f, 0.f, 0.f, 0.f);
        GArgs gF = mk(Pmb, x0T, Ff, nullptr, Fb, nullptr, nullptr, FTb,
                      x0, nf, nu, n, h, n, h / 32, n / 64,
                      dt, dt, 0.f, 0.f, 0.f, 0.f, 0.f, 0.f, 0.f, 0.f);
        gemm2<2, 1, 6><<<dim3(512 + 1024), blk, 0, stream>>>(gB2, gF, 512);
    }

    // ===== P3: B3 (h^3, FIRST) || u (K=2048) =====
    // B3: acc = XB^3; MbT = acc/6 + XB + XB^2/2 (CbT); P3 = acc (C2+Cb2)
    // u = Ma@F + F -> ub
    {
        GArgs gB3 = mk(P2b, XBT, nullptr, P3f, nullptr, P3b, nullptr, MbT,
                       XBf, P2f, nu, h, h, h, h / 32, h / 64,
                       1.f / 6.f, 1.f, 0.5f, 0.f, 1.f, 0.f, 0.f, 0.f, 0.f, 0.f);
        GArgs gU = mk(Mah, FTb, nullptr, nullptr, ub, nullptr, nullptr, nullptr,
                      nf, nf, Fb, n, h, n, h / 32, n / 64,
                      1.f, 0.f, 0.f, 1.f, 0.f, 0.f, 0.f, 0.f, 0.f, 0.f);
        gemm2<2, 1, 6><<<dim3(512 + 1024), blk, 0, stream>>>(gB3, gU, 512);
    }

    // ===== P4: B4 (h^3, FIRST) || F2 (K=1024) =====
    // B4: acc = XB^4; M3bT = 3.375 acc + 4.5 XB^3 + 4.5 XB^2 + 3 XB
    // F2 = u@Mb + u + F -> F2b + F2Tb
    {
        GArgs gB4 = mk(P3b, XBT, nullptr, nullptr, nullptr, nullptr, nullptr, M3bTb,
                       P3f, P2f, XBb, h, h, h, h / 32, h / 64,
                       3.375f, 4.5f, 4.5f, 3.f, 0.f, 0.f, 0.f, 0.f, 0.f, 0.f);
        GArgs gF2 = mk(ub, MbT, nullptr, nullptr, F2b, nullptr, nullptr, F2Tb,
                       nf, Ff, ub, n, h, h, h / 32, n / 64,
                       1.f, 0.f, 1.f, 1.f, 0.f, 0.f, 0.f, 0.f, 0.f, 0.f);
        gemm2<2, 1, 6><<<dim3(512 + 1024), blk, 0, stream>>>(gB4, gF2, 512);
    }

    // ===== P5: v (K=2048) || G1 step 0 (K=2048) =====
    {
        GArgs gV = mk(Mah, F2Tb, nullptr, nullptr, vb, nullptr, nullptr, nullptr,
                      nf, nf, F2b, n, h, n, h / 32, n / 64,
                      1.f, 0.f, 0.f, 1.f, 0.f, 0.f, 0.f, 0.f, 0.f, 0.f);
        GArgs gG1 = mk(M3ah, zt, nullptr, nullptr, tb16, nullptr, nullptr, nullptr,
                       x, nf, nu, n, h, n, h / 32, n / 64,
                       1.f, 1.f, 0.f, 0.f, 0.f, 0.f, 0.f, 0.f, 0.f, 0.f);
        gemm2<2, 1, 6><<<dim3(1024 + 1024), blk, 0, stream>>>(gV, gG1, 1024);
    }

    // ===== F3 = v@Mb + v + F (K=1024) =====
    {
        GArgs g = mk(vb, MbT, F3f, nullptr, nullptr, nullptr, nullptr, nullptr,
                     nf, Ff, vb, n, h, h, h / 32, n / 64,
                     1.f, 0.f, 1.f, 1.f, 0.f, 0.f, 0.f, 0.f, 0.f, 0.f);
        gemm2<2, 1, 6><<<dim3(1024), blk, 0, stream>>>(g, g, 1024);
    }

    // ===== scan remainder: G2, (G1, G2) x 2 =====
    for (int s = 0; s < 3; ++s) {
        if (s > 0) {
            // G1: t = M3a@z + z -> tb16
            GArgs g = mk(M3ah, zt, nullptr, nullptr, tb16, nullptr, nullptr,
                         nullptr, za, nf, nu, n, h, n, h / 32, n / 64,
                         1.f, 1.f, 0.f, 0.f, 0.f, 0.f, 0.f, 0.f, 0.f, 0.f);
            gemm2<2, 1, 6><<<dim3(1024), blk, 0, stream>>>(g, g, 1024);
        }
        // G2: z''' = t@M3b + t + F3 -> za (+ zt for next step) [last: d_out]
        float* zout = (s == 2) ? (float*)d_out : za;
        GArgs g = mk(tb16, M3bTb, zout, nullptr, nullptr, nullptr, nullptr,
                     (s == 2) ? nullptr : zt, nf, F3f, tb16,
                     n, h, h, h / 32, n / 64,
                     1.f, 0.f, 1.f, 1.f, 0.f, 0.f, 0.f, 0.f, 0.f, 0.f);
        gemm2<2, 1, 6><<<dim3(1024), blk, 0, stream>>>(g, g, 1024);
    }
}